// Round 15
// baseline (2588.415 us; speedup 1.0000x reference)
//
#include <hip/hip_runtime.h>
#include <hip/hip_bf16.h>

// GraphSAGE inference, MI355X. R15: R14 dataflow, single mega-launch for
// phases 1..E with device-scope atomic signaling (G16 recipe).
//  P0  : gather_self(Hall) | weights cast | zero(out) | zero(counters)
//  MEGA: [0,832)      self-GEMM (XCD-map; P cols 0-511 / C0; signal cntS)
//        [832,13632)  mean10 -> Hmall rows<25600   (signal cnt[rowblk])
//        [13632,14144) H0m   -> Hmall rows 25600+  (signal cnt[200+..])
//        [14144,14976) ngemm (spin cnt[rb]==64; P cols 512+ / C0; signal cntN)
//        [14976,16000) M1-reduce (spin cntS,cntN==832; M1=bf16(P/25); signal cntM)
//        [16000,16064) gemm1-pass0 (spin cntS,cntN; out += C0@Ws1)
//        [16064,16128) gemm1-pass1 (spin cntM==1024; out += M1@Wn1)
// Consumers are after producers in blockIdx order; consumers alone can't fill
// the device => producers always progress => no deadlock.

#define DEVINL __device__ __forceinline__

typedef __bf16 bf16x8 __attribute__((ext_vector_type(8)));
typedef float f32x4 __attribute__((ext_vector_type(4)));

DEVINL unsigned short f2bf(float f) {
  union { float f; unsigned u; } v; v.f = f;
  unsigned r = v.u + 0x7FFFu + ((v.u >> 16) & 1u);  // RNE
  return (unsigned short)(r >> 16);
}
DEVINL float bf2f(unsigned short h) {
  union { unsigned u; float f; } v; v.u = ((unsigned)h) << 16;
  return v.f;
}

DEVINL void gload_lds16(const void* g, void* l) {
  __builtin_amdgcn_global_load_lds(
      (const __attribute__((address_space(1))) void*)g,
      (__attribute__((address_space(3))) void*)l, 16, 0, 0);
}

// release-signal: every thread drains its stores, then one lane increments.
DEVINL void signal_cnt(unsigned* c, int tid) {
  __threadfence();
  __syncthreads();
  if (tid == 0) atomicAdd(c, 1u);
}
// acquire-spin: one lane polls (with backoff), block syncs, all lanes fence.
DEVINL void spin_cnt(unsigned* c, unsigned target, int tid) {
  if (tid == 0) {
    while (atomicAdd(c, 0u) < target) __builtin_amdgcn_s_sleep(8);
  }
  __syncthreads();
  __threadfence();
}

// ---- NT GEMM core: 128x128 tile, BK=32, 4 waves 2x2, 16x16x32 bf16 MFMA.
// EPI 0 (layer0): rows<25600 -> static-reg group-sum -> P[wh][slot][col] (relu'd);
//                 rows>=25600 -> bf16 store to C0[row-25600][col0+...].
// EPI 1 (layer1): f32 atomicAdd into out (split-K).
template <int EPI>
DEVINL void gemm_core(const unsigned short* __restrict__ A, int lda,
                      const unsigned short* __restrict__ Bt, int ldb,
                      int Kc, long tm, long tn, int col0,
                      unsigned short* __restrict__ C0, float* __restrict__ P,
                      float* __restrict__ out, int ldc,
                      unsigned short* As, unsigned short* Bs) {
  const int t = threadIdx.x;
  const int w = t >> 6;
  const int l = t & 63;
  const int wm = w >> 1, wn = w & 1;
  f32x4 acc[4][4] = {};
  const int s_r = l >> 2;
  const int s_kc = (l & 3) * 8;

  for (int kt = 0; kt < Kc; kt += 32) {
    __syncthreads();  // LDS free
    #pragma unroll
    for (int r = 0; r < 2; ++r) {
      const int chunk = r * 64 + w * 16;
      gload_lds16(A + (size_t)(tm + chunk + s_r) * lda + kt + s_kc, As + chunk * 32);
      gload_lds16(Bt + (size_t)(tn + chunk + s_r) * ldb + kt + s_kc, Bs + chunk * 32);
    }
    __syncthreads();  // staged

    bf16x8 af[4], bfr[4];
    const unsigned short* Ab = As + ((size_t)(wm * 64 + (l & 15)) * 32 + (l >> 4) * 8);
    const unsigned short* Bb = Bs + ((size_t)(wn * 64 + (l & 15)) * 32 + (l >> 4) * 8);
    #pragma unroll
    for (int f = 0; f < 4; ++f) {
      af[f] = *reinterpret_cast<const bf16x8*>(Ab + f * 16 * 32);
      bfr[f] = *reinterpret_cast<const bf16x8*>(Bb + f * 16 * 32);
    }
    #pragma unroll
    for (int i = 0; i < 4; ++i)
      #pragma unroll
      for (int j = 0; j < 4; ++j)
        acc[i][j] = __builtin_amdgcn_mfma_f32_16x16x32_bf16(af[i], bfr[j], acc[i][j], 0, 0, 0);
  }

  // epilogue: C/D layout col = l&15, row = (l>>4)*4 + r  [m89/m91 verified]
  const int q = l >> 4, cl = l & 15;
  if (EPI == 0) {
    if (tm < 25600) {
      const int wmBase = (int)tm + wm * 64;
      const int g0w = wmBase / 25;
      float gacc[4][4] = {};  // [j][slot], static indices only (rule #20)
      #pragma unroll
      for (int i = 0; i < 4; ++i)
        #pragma unroll
        for (int r = 0; r < 4; ++r) {
          const int gl = (wmBase + i * 16 + q * 4 + r) / 25 - g0w;  // 0..3
          #pragma unroll
          for (int j = 0; j < 4; ++j) {
            const float v = fmaxf(acc[i][j][r], 0.f);
            #pragma unroll
            for (int slot = 0; slot < 4; ++slot)
              gacc[j][slot] += (gl == slot) ? v : 0.f;
          }
        }
      #pragma unroll
      for (int j = 0; j < 4; ++j)
        #pragma unroll
        for (int slot = 0; slot < 4; ++slot) {
          float v = gacc[j][slot];
          v += __shfl_xor(v, 16);
          v += __shfl_xor(v, 32);
          gacc[j][slot] = v;
        }
      if (q == 0) {
        const int wh = wmBase >> 6;
        #pragma unroll
        for (int slot = 0; slot < 4; ++slot)
          #pragma unroll
          for (int j = 0; j < 4; ++j)
            P[((size_t)wh * 4 + slot) * 1024 + col0 + tn + wn * 64 + j * 16 + cl] = gacc[j][slot];
      }
    } else {
      #pragma unroll
      for (int i = 0; i < 4; ++i)
        #pragma unroll
        for (int j = 0; j < 4; ++j)
          #pragma unroll
          for (int r = 0; r < 4; ++r) {
            const long row = tm - 25600 + wm * 64 + i * 16 + q * 4 + r;
            const long col = col0 + tn + wn * 64 + j * 16 + cl;
            C0[row * 1024 + col] = f2bf(fmaxf(acc[i][j][r], 0.f));
          }
    }
  } else {
    #pragma unroll
    for (int i = 0; i < 4; ++i)
      #pragma unroll
      for (int j = 0; j < 4; ++j)
        #pragma unroll
        for (int r = 0; r < 4; ++r) {
          const long row = tm + wm * 64 + i * 16 + q * 4 + r;
          const long col = tn + wn * 64 + j * 16 + cl;
          atomicAdd(out + row * ldc + col, acc[i][j][r]);
        }
  }
}

// XCD-clustered tile map for 832 = 208 rowblocks x 4 colblocks (R11).
DEVINL void xcd_tile_map(int b, long& tm, long& tn) {
  const int xcd = b & 7, idx = b >> 3;
  tm = (long)(xcd + 8 * (idx >> 2)) * 128;
  tn = (long)(idx & 3) * 128;
}

// ---- P0: gather_self (13312) | weights (4096) | zero out (256) | zero counters (1)
__global__ __launch_bounds__(256) void phase0_kernel(
    const float* __restrict__ x, const int* __restrict__ neigh1, const int* __restrict__ nodes,
    const float* __restrict__ Ws0, const float* __restrict__ Wn0,
    const float* __restrict__ Ws1, const float* __restrict__ Wn1,
    unsigned short* __restrict__ Hall,
    unsigned short* __restrict__ WT0s, unsigned short* __restrict__ WT0n,
    unsigned short* __restrict__ WT1s, unsigned short* __restrict__ WT1n,
    float* __restrict__ out, unsigned* __restrict__ cnt) {
  const int b = blockIdx.x;
  const int tid = threadIdx.x;
  if (b < 13312) {
    int row = b * 2 + (tid >> 7);
    int src = row < 25600 ? neigh1[row] : nodes[row - 25600];
    int c4 = (tid & 127) << 2;
    const float4 v = *reinterpret_cast<const float4*>(x + (size_t)src * 512 + c4);
    ushort4 o; o.x = f2bf(v.x); o.y = f2bf(v.y); o.z = f2bf(v.z); o.w = f2bf(v.w);
    *reinterpret_cast<ushort4*>(Hall + (size_t)row * 512 + c4) = o;
  } else if (b < 13312 + 4096) {
    int t = (b - 13312) * 256 + tid;
    int region = t >> 18, local = t & 262143;
    const float* W; unsigned short* WT;
    if (region == 0)      { W = Ws0; WT = WT0s; }
    else if (region == 1) { W = Wn0; WT = WT0n; }
    else if (region == 2) { W = Ws1; WT = WT1s; }
    else                  { W = Wn1; WT = WT1n; }
    int k, n, N;
    if (region < 2) { k = local & 511;  n = local >> 9;  N = 512; }
    else            { k = local & 1023; n = local >> 10; N = 256; }
    WT[local] = f2bf(W[(size_t)k * N + n]);
  } else if (b < 17664) {
    int t = (b - 17408) * 256 + tid;
    reinterpret_cast<float4*>(out)[t] = float4{0.f, 0.f, 0.f, 0.f};
  } else {  // zero 256 counter slots (211 used)
    cnt[tid] = 0u;
  }
}

// ---- mean10 of x rows -> bf16 Hmall row
DEVINL void mean10_row(const float* __restrict__ x, const int* __restrict__ neigh2,
                       unsigned short* __restrict__ Hmall, int row, int tid) {
  int c4 = (tid & 127) << 2;
  float4 acc = {0.f, 0.f, 0.f, 0.f};
  const int* ip = neigh2 + (size_t)row * 10;
  #pragma unroll
  for (int j = 0; j < 10; ++j) {
    const float4 v = *reinterpret_cast<const float4*>(x + (size_t)ip[j] * 512 + c4);
    acc.x += v.x; acc.y += v.y; acc.z += v.z; acc.w += v.w;
  }
  const float s = 0.1f;
  ushort4 o; o.x = f2bf(acc.x * s); o.y = f2bf(acc.y * s);
  o.z = f2bf(acc.z * s); o.w = f2bf(acc.w * s);
  *reinterpret_cast<ushort4*>(Hmall + (size_t)row * 512 + c4) = o;
}

// ---- MEGA kernel: see header map. cnt[0..207]=rowblock, 208=cntS, 209=cntN, 210=cntM.
__global__ __launch_bounds__(256) void mega_kernel(
    const float* __restrict__ x, const int* __restrict__ neigh2,
    const unsigned short* __restrict__ Hall,
    const unsigned short* __restrict__ WT0s, const unsigned short* __restrict__ WT0n,
    const unsigned short* __restrict__ WT1s, const unsigned short* __restrict__ WT1n,
    unsigned short* __restrict__ Hmall,
    unsigned short* __restrict__ C0, float* __restrict__ P,
    unsigned short* __restrict__ M1, float* __restrict__ out,
    unsigned* __restrict__ cnt) {
  __shared__ __align__(16) unsigned short As[128 * 32];
  __shared__ __align__(16) unsigned short Bs[128 * 32];
  const int b = blockIdx.x;
  const int tid = threadIdx.x;

  if (b < 832) {  // ---- self-GEMM (inputs ready from P0)
    long tm, tn;
    xcd_tile_map(b, tm, tn);
    gemm_core<0>(Hall, 512, WT0s, 512, 512, tm, tn, 0, C0, P, nullptr, 0, As, Bs);
    signal_cnt(cnt + 208, tid);
  } else if (b < 13632) {  // ---- mean10 rows 0-25599
    const int u = b - 832;
    mean10_row(x, neigh2, Hmall, u * 2 + (tid >> 7), tid);
    signal_cnt(cnt + (u >> 6), tid);            // rowblock u>>6 (0..199), 64 units each
  } else if (b < 14144) {  // ---- H0m: mean25(Hall) -> Hmall rows 25600+
    const int s0 = b - 13632;                   // 0..511
    int g = s0 * 2 + (tid >> 7);
    int c4 = (tid & 127) << 2;
    float a0 = 0, a1 = 0, a2 = 0, a3 = 0;
    for (int j = 0; j < 25; ++j) {
      ushort4 v = *reinterpret_cast<const ushort4*>(Hall + ((size_t)g * 25 + j) * 512 + c4);
      a0 += bf2f(v.x); a1 += bf2f(v.y); a2 += bf2f(v.z); a3 += bf2f(v.w);
    }
    const float s = 1.0f / 25.0f;
    ushort4 o; o.x = f2bf(a0 * s); o.y = f2bf(a1 * s); o.z = f2bf(a2 * s); o.w = f2bf(a3 * s);
    *reinterpret_cast<ushort4*>(Hmall + ((size_t)25600 + g) * 512 + c4) = o;
    signal_cnt(cnt + 200 + (s0 >> 6), tid);     // rowblocks 200..207, 64 units each
  } else if (b < 14976) {  // ---- ngemm (spin on its A rowblock)
    long tm, tn;
    xcd_tile_map(b - 14144, tm, tn);
    spin_cnt(cnt + (int)(tm >> 7), 64u, tid);
    gemm_core<0>(Hmall, 512, WT0n, 512, 512, tm, tn, 512, C0, P, nullptr, 0, As, Bs);
    signal_cnt(cnt + 209, tid);
  } else if (b < 16000) {  // ---- M1-reduce (needs all P partials)
    spin_cnt(cnt + 208, 832u, tid);
    spin_cnt(cnt + 209, 832u, tid);
    const int g = b - 14976;
    const int c = tid << 2;
    const int wh0 = (g * 25) >> 6, wh1 = (g * 25 + 24) >> 6;
    f32x4 s = {0.f, 0.f, 0.f, 0.f};
    for (int wh = wh0; wh <= wh1; ++wh) {
      const int slot = g - (wh * 64) / 25;
      const f32x4 v = *reinterpret_cast<const f32x4*>(P + ((size_t)wh * 4 + slot) * 1024 + c);
      s[0] += v[0]; s[1] += v[1]; s[2] += v[2]; s[3] += v[3];
    }
    const float sc = 1.0f / 25.0f;
    ushort4 o; o.x = f2bf(s[0] * sc); o.y = f2bf(s[1] * sc);
    o.z = f2bf(s[2] * sc); o.w = f2bf(s[3] * sc);
    *reinterpret_cast<ushort4*>(M1 + (size_t)g * 1024 + c) = o;
    signal_cnt(cnt + 210, tid);
  } else if (b < 16064) {  // ---- gemm1-pass0: out += C0@Ws1 (needs full C0)
    spin_cnt(cnt + 208, 832u, tid);
    spin_cnt(cnt + 209, 832u, tid);
    const int u = b - 16000;
    const int z = u >> 4, bm = (u >> 1) & 7, bn = u & 1;
    gemm_core<1>(C0 + z * 256, 1024, WT1s + z * 256, 1024, 256,
                 (long)bm * 128, (long)bn * 128, 0, nullptr, nullptr, out, 256, As, Bs);
  } else {  // ---- gemm1-pass1: out += M1@Wn1 (needs M1)
    spin_cnt(cnt + 210, 1024u, tid);
    const int u = b - 16064;
    const int z = u >> 4, bm = (u >> 1) & 7, bn = u & 1;
    gemm_core<1>(M1 + z * 256, 1024, WT1n + z * 256, 1024, 256,
                 (long)bm * 128, (long)bn * 128, 0, nullptr, nullptr, out, 256, As, Bs);
  }
}

extern "C" void kernel_launch(void* const* d_in, const int* in_sizes, int n_in,
                              void* d_out, int out_size, void* d_ws, size_t ws_size,
                              hipStream_t stream) {
  const float* x      = (const float*)d_in[0];   // [200000, 512]
  const int*   nodes  = (const int*)d_in[1];     // [1024]
  const int*   neigh1 = (const int*)d_in[2];     // [25600]
  const int*   neigh2 = (const int*)d_in[3];     // [256000]
  const float* Ws0    = (const float*)d_in[4];   // [512, 512]
  const float* Wn0    = (const float*)d_in[5];   // [512, 512]
  const float* Ws1    = (const float*)d_in[6];   // [1024, 256]
  const float* Wn1    = (const float*)d_in[7];   // [1024, 256]
  float* out = (float*)d_out;                    // [1024, 256]

  char* p = (char*)d_ws;
  unsigned short* WT0s  = (unsigned short*)p; p += (size_t)512 * 512 * 2;
  unsigned short* WT0n  = (unsigned short*)p; p += (size_t)512 * 512 * 2;
  unsigned short* WT1s  = (unsigned short*)p; p += (size_t)256 * 1024 * 2;
  unsigned short* WT1n  = (unsigned short*)p; p += (size_t)256 * 1024 * 2;
  unsigned short* Hall  = (unsigned short*)p; p += (size_t)26624 * 512 * 2;
  unsigned short* Hmall = (unsigned short*)p; p += (size_t)26624 * 512 * 2;
  unsigned short* C0    = (unsigned short*)p; p += (size_t)1024 * 1024 * 2;
  unsigned short* M1    = (unsigned short*)p; p += (size_t)1024 * 1024 * 2;
  float*          P     = (float*)p;          p += (size_t)400 * 4 * 1024 * 4;
  unsigned*       cnt   = (unsigned*)p;       p += 256 * 4;

  hipLaunchKernelGGL(phase0_kernel, dim3(17665), dim3(256), 0, stream,
                     x, neigh1, nodes, Ws0, Wn0, Ws1, Wn1,
                     Hall, WT0s, WT0n, WT1s, WT1n, out, cnt);
  hipLaunchKernelGGL(mega_kernel, dim3(16128), dim3(256), 0, stream,
                     x, neigh2, Hall, WT0s, WT0n, WT1s, WT1n,
                     Hmall, C0, P, M1, out, cnt);
}

// Round 16
// 173.488 us; speedup vs baseline: 14.9198x; 14.9198x over previous
//
#include <hip/hip_runtime.h>
#include <hip/hip_bf16.h>

// GraphSAGE inference, MI355X. R16: R14 dataflow, M1 eliminated.
//  P0: gather_self(Hall) | weights cast | zero(out)
//  P1: gemm0-SELF (XCD-map; rows<25600 -> P partials, rows>=25600 -> C0)
//      || gather_mean10 || mean25(Hall)->H0m
//  P2: gemm0-NEIGHBOR (same epilogue, cols 512+)
//  PD: gemm1-pass0 (out += C0@Ws1) | gemm1-pass1 (out += mean25P@Wn1,
//      A-tile staged from P with inline reduce -> identical bf16 as R14's M1)
// P layout: P[wh][slot][1024] f32, wh = 64-row half-tile (0..399), slot = local
// group (0..3). Each slot written exactly once (no atomics).

#define DEVINL __device__ __forceinline__

typedef __bf16 bf16x8 __attribute__((ext_vector_type(8)));
typedef float f32x4 __attribute__((ext_vector_type(4)));
typedef unsigned short u16x8 __attribute__((ext_vector_type(8)));

DEVINL unsigned short f2bf(float f) {
  union { float f; unsigned u; } v; v.f = f;
  unsigned r = v.u + 0x7FFFu + ((v.u >> 16) & 1u);  // RNE
  return (unsigned short)(r >> 16);
}
DEVINL float bf2f(unsigned short h) {
  union { unsigned u; float f; } v; v.u = ((unsigned)h) << 16;
  return v.f;
}

DEVINL void gload_lds16(const void* g, void* l) {
  __builtin_amdgcn_global_load_lds(
      (const __attribute__((address_space(1))) void*)g,
      (__attribute__((address_space(3))) void*)l, 16, 0, 0);
}

// ---- NT GEMM core: 128x128 tile, BK in {32,64}, 4 waves 2x2, 16x16x32 bf16 MFMA.
// EPI 0 (layer0): rows<25600 -> static-reg group-sum -> P[wh][slot][col] (relu'd);
//                 rows>=25600 -> bf16 store to C0[row-25600][col0+...].
// EPI 1 (layer1): A staged via gload; f32 atomicAdd into out (split-K).
// EPI 2 (layer1): A staged FROM P with inline mean25 reduce (col0 = global k0);
//                 f32 atomicAdd into out.
template <int EPI, int BK>
DEVINL void gemm_core(const unsigned short* __restrict__ A, int lda,
                      const unsigned short* __restrict__ Bt, int ldb,
                      int Kc, long tm, long tn, int col0,
                      unsigned short* __restrict__ C0, float* __restrict__ P,
                      float* __restrict__ out, int ldc,
                      unsigned short* As, unsigned short* Bs) {
  const int t = threadIdx.x;
  const int w = t >> 6;
  const int l = t & 63;
  const int wm = w >> 1, wn = w & 1;
  f32x4 acc[4][4] = {};
  constexpr int LPR = BK / 8;            // lanes per row (16B chunks)
  constexpr int RPW = 64 / LPR;          // rows per wave-gload
  constexpr int ROUNDS = 128 / (4 * RPW);
  constexpr int NS = BK / 32;            // k-slices per iter
  const int s_r = l / LPR;
  const int s_kc = (l % LPR) * 8;

  for (int kt = 0; kt < Kc; kt += BK) {
    __syncthreads();  // LDS free
    #pragma unroll
    for (int r = 0; r < ROUNDS; ++r) {
      const int chunk = r * (4 * RPW) + w * RPW;
      if (EPI != 2) {
        gload_lds16(A + (size_t)(tm + chunk + s_r) * lda + kt + s_kc, As + chunk * BK);
      } else {
        // A-from-P: lane computes 8 bf16 = f2bf(sum_wh P[wh][slot][k] / 25)
        // -> identical values to R14's M1. LDS slot matches gload lane layout.
        const int g = (int)tm + chunk + s_r;          // group row 0..1023
        const int k = col0 + kt + s_kc;               // global K col, 8 consecutive
        const int wh0 = (g * 25) >> 6, wh1 = (g * 25 + 24) >> 6;
        float s0 = 0, s1 = 0, s2 = 0, s3 = 0, s4 = 0, s5 = 0, s6 = 0, s7 = 0;
        for (int wh = wh0; wh <= wh1; ++wh) {         // <=2 iters
          const int slot = g - (wh * 64) / 25;        // 0..3
          const float* src = P + ((size_t)(wh * 4 + slot)) * 1024 + k;
          const f32x4 v0 = *reinterpret_cast<const f32x4*>(src);
          const f32x4 v1 = *reinterpret_cast<const f32x4*>(src + 4);
          s0 += v0[0]; s1 += v0[1]; s2 += v0[2]; s3 += v0[3];
          s4 += v1[0]; s5 += v1[1]; s6 += v1[2]; s7 += v1[3];
        }
        const float sc = 1.0f / 25.0f;
        u16x8 hv;
        hv[0] = f2bf(s0 * sc); hv[1] = f2bf(s1 * sc); hv[2] = f2bf(s2 * sc);
        hv[3] = f2bf(s3 * sc); hv[4] = f2bf(s4 * sc); hv[5] = f2bf(s5 * sc);
        hv[6] = f2bf(s6 * sc); hv[7] = f2bf(s7 * sc);
        *reinterpret_cast<u16x8*>(As + chunk * BK + l * 8) = hv;
      }
      gload_lds16(Bt + (size_t)(tn + chunk + s_r) * ldb + kt + s_kc, Bs + chunk * BK);
    }
    __syncthreads();  // staged (barrier drains vmcnt + lgkmcnt)

    bf16x8 af[4][NS], bfr[4][NS];
    const unsigned short* Ab = As + ((size_t)(wm * 64 + (l & 15)) * BK + (l >> 4) * 8);
    const unsigned short* Bb = Bs + ((size_t)(wn * 64 + (l & 15)) * BK + (l >> 4) * 8);
    #pragma unroll
    for (int f = 0; f < 4; ++f)
      #pragma unroll
      for (int s = 0; s < NS; ++s) {
        af[f][s] = *reinterpret_cast<const bf16x8*>(Ab + f * 16 * BK + s * 32);
        bfr[f][s] = *reinterpret_cast<const bf16x8*>(Bb + f * 16 * BK + s * 32);
      }
    #pragma unroll
    for (int s = 0; s < NS; ++s)   // K ascending (matches prior rounds' numerics)
      #pragma unroll
      for (int i = 0; i < 4; ++i)
        #pragma unroll
        for (int j = 0; j < 4; ++j)
          acc[i][j] = __builtin_amdgcn_mfma_f32_16x16x32_bf16(af[i][s], bfr[j][s], acc[i][j], 0, 0, 0);
  }

  // epilogue: C/D layout col = l&15, row = (l>>4)*4 + r  [m89/m91 verified]
  const int q = l >> 4, cl = l & 15;
  if (EPI == 0) {
    if (tm < 25600) {
      // register group-sum, ALL indices compile-time (rule #20: no scratch).
      const int wmBase = (int)tm + wm * 64;
      const int g0w = wmBase / 25;
      float gacc[4][4] = {};  // [j][slot], statically indexed only
      #pragma unroll
      for (int i = 0; i < 4; ++i)
        #pragma unroll
        for (int r = 0; r < 4; ++r) {
          const int gl = (wmBase + i * 16 + q * 4 + r) / 25 - g0w;  // runtime 0..3
          #pragma unroll
          for (int j = 0; j < 4; ++j) {
            const float v = fmaxf(acc[i][j][r], 0.f);
            #pragma unroll
            for (int slot = 0; slot < 4; ++slot)
              gacc[j][slot] += (gl == slot) ? v : 0.f;   // cndmask+add
          }
        }
      #pragma unroll
      for (int j = 0; j < 4; ++j)
        #pragma unroll
        for (int slot = 0; slot < 4; ++slot) {
          float v = gacc[j][slot];
          v += __shfl_xor(v, 16);
          v += __shfl_xor(v, 32);
          gacc[j][slot] = v;
        }
      if (q == 0) {  // 16 lanes x 4 j x 4 slots
        const int wh = wmBase >> 6;
        #pragma unroll
        for (int slot = 0; slot < 4; ++slot)
          #pragma unroll
          for (int j = 0; j < 4; ++j)
            P[((size_t)wh * 4 + slot) * 1024 + col0 + tn + wn * 64 + j * 16 + cl] = gacc[j][slot];
      }
    } else {
      #pragma unroll
      for (int i = 0; i < 4; ++i)
        #pragma unroll
        for (int j = 0; j < 4; ++j)
          #pragma unroll
          for (int r = 0; r < 4; ++r) {
            const long row = tm - 25600 + wm * 64 + i * 16 + q * 4 + r;
            const long col = col0 + tn + wn * 64 + j * 16 + cl;
            C0[row * 1024 + col] = f2bf(fmaxf(acc[i][j][r], 0.f));
          }
    }
  } else {
    #pragma unroll
    for (int i = 0; i < 4; ++i)
      #pragma unroll
      for (int j = 0; j < 4; ++j)
        #pragma unroll
        for (int r = 0; r < 4; ++r) {
          const long row = tm + wm * 64 + i * 16 + q * 4 + r;
          const long col = tn + wn * 64 + j * 16 + cl;
          atomicAdd(out + row * ldc + col, acc[i][j][r]);
        }
  }
}

// XCD-clustered tile map for 832 = 208 rowblocks x 4 colblocks (R11, kept).
DEVINL void xcd_tile_map(int b, long& tm, long& tn) {
  const int xcd = b & 7, idx = b >> 3;
  tm = (long)(xcd + 8 * (idx >> 2)) * 128;
  tn = (long)(idx & 3) * 128;
}

// ---- mean10 of x rows -> bf16 Hmall row (2 rows/block, 256 thr)
DEVINL void mean10_row(const float* __restrict__ x, const int* __restrict__ neigh2,
                       unsigned short* __restrict__ Hmall, int row, int tid) {
  int c4 = (tid & 127) << 2;
  float4 acc = {0.f, 0.f, 0.f, 0.f};
  const int* ip = neigh2 + (size_t)row * 10;
  #pragma unroll
  for (int j = 0; j < 10; ++j) {
    const float4 v = *reinterpret_cast<const float4*>(x + (size_t)ip[j] * 512 + c4);
    acc.x += v.x; acc.y += v.y; acc.z += v.z; acc.w += v.w;
  }
  const float s = 0.1f;
  ushort4 o; o.x = f2bf(acc.x * s); o.y = f2bf(acc.y * s);
  o.z = f2bf(acc.z * s); o.w = f2bf(acc.w * s);
  *reinterpret_cast<ushort4*>(Hmall + (size_t)row * 512 + c4) = o;
}

// ---- P0: gather_self (13312) | weights cast (4096) | zero out (256)
__global__ __launch_bounds__(256) void phase0_kernel(
    const float* __restrict__ x, const int* __restrict__ neigh1, const int* __restrict__ nodes,
    const float* __restrict__ Ws0, const float* __restrict__ Wn0,
    const float* __restrict__ Ws1, const float* __restrict__ Wn1,
    unsigned short* __restrict__ Hall,
    unsigned short* __restrict__ WT0s, unsigned short* __restrict__ WT0n,
    unsigned short* __restrict__ WT1s, unsigned short* __restrict__ WT1n,
    float* __restrict__ out) {
  const int b = blockIdx.x;
  const int tid = threadIdx.x;
  if (b < 13312) {  // gather_self: 2 rows/block
    int row = b * 2 + (tid >> 7);
    int src = row < 25600 ? neigh1[row] : nodes[row - 25600];
    int c4 = (tid & 127) << 2;
    const float4 v = *reinterpret_cast<const float4*>(x + (size_t)src * 512 + c4);
    ushort4 o; o.x = f2bf(v.x); o.y = f2bf(v.y); o.z = f2bf(v.z); o.w = f2bf(v.w);
    *reinterpret_cast<ushort4*>(Hall + (size_t)row * 512 + c4) = o;
  } else if (b < 13312 + 4096) {  // weights -> bf16 [N][K]
    int t = (b - 13312) * 256 + tid;
    int region = t >> 18, local = t & 262143;
    const float* W; unsigned short* WT;
    if (region == 0)      { W = Ws0; WT = WT0s; }
    else if (region == 1) { W = Wn0; WT = WT0n; }
    else if (region == 2) { W = Ws1; WT = WT1s; }
    else                  { W = Wn1; WT = WT1n; }
    int k, n, N;
    if (region < 2) { k = local & 511;  n = local >> 9;  N = 512; }
    else            { k = local & 1023; n = local >> 10; N = 256; }
    WT[local] = f2bf(W[(size_t)k * N + n]);
  } else {  // zero out (1 MB)
    int t = (b - 17408) * 256 + tid;
    reinterpret_cast<float4*>(out)[t] = float4{0.f, 0.f, 0.f, 0.f};
  }
}

// ---- P1: gemm0-self (832, XCD-clustered) | gather_mean10 (12800) | mean25(Hall)->H0m (512)
__global__ __launch_bounds__(256) void phase1_kernel(
    const float* __restrict__ x, const int* __restrict__ neigh2,
    const unsigned short* __restrict__ Hall, const unsigned short* __restrict__ WT0s,
    unsigned short* __restrict__ Hmall,
    unsigned short* __restrict__ C0, float* __restrict__ P) {
  __shared__ __align__(16) unsigned short As[128 * 32];
  __shared__ __align__(16) unsigned short Bs[128 * 32];
  const int b = blockIdx.x;
  const int tid = threadIdx.x;
  if (b < 832) {  // self half: cols 0-511, all 26624 rows
    long tm, tn;
    xcd_tile_map(b, tm, tn);
    gemm_core<0, 32>(Hall, 512, WT0s, 512, 512, tm, tn, 0, C0, P, nullptr, 0, As, Bs);
  } else if (b < 832 + 12800) {  // mean10 rows 0-25599
    mean10_row(x, neigh2, Hmall, (b - 832) * 2 + (tid >> 7), tid);
  } else {  // H0m = mean25 of Hall bf16 rows -> Hmall rows 25600+
    int g = (b - 13632) * 2 + (tid >> 7);
    int c4 = (tid & 127) << 2;
    float a0 = 0, a1 = 0, a2 = 0, a3 = 0;
    for (int j = 0; j < 25; ++j) {
      ushort4 v = *reinterpret_cast<const ushort4*>(Hall + ((size_t)g * 25 + j) * 512 + c4);
      a0 += bf2f(v.x); a1 += bf2f(v.y); a2 += bf2f(v.z); a3 += bf2f(v.w);
    }
    const float s = 1.0f / 25.0f;
    ushort4 o; o.x = f2bf(a0 * s); o.y = f2bf(a1 * s); o.z = f2bf(a2 * s); o.w = f2bf(a3 * s);
    *reinterpret_cast<ushort4*>(Hmall + ((size_t)25600 + g) * 512 + c4) = o;
  }
}

// ---- P2: gemm0 neighbor half (832, XCD-clustered): cols 512-1023
__global__ __launch_bounds__(256) void phase2_kernel(
    const unsigned short* __restrict__ Hmall, const unsigned short* __restrict__ WT0n,
    unsigned short* __restrict__ C0, float* __restrict__ P) {
  __shared__ __align__(16) unsigned short As[128 * 32];
  __shared__ __align__(16) unsigned short Bs[128 * 32];
  long tm, tn;
  xcd_tile_map(blockIdx.x, tm, tn);
  gemm_core<0, 32>(Hmall, 512, WT0n, 512, 512, tm, tn, 512, C0, P, nullptr, 0, As, Bs);
}

// ---- PD: gemm1-pass0 (64: out += C0@Ws1) | gemm1-pass1 (64: out += mean25P@Wn1)
__global__ __launch_bounds__(256) void phaseD_kernel(
    const unsigned short* __restrict__ C0, const unsigned short* __restrict__ WT1s,
    const unsigned short* __restrict__ WT1n, float* __restrict__ P,
    float* __restrict__ out) {
  __shared__ __align__(16) unsigned short As[128 * 64];
  __shared__ __align__(16) unsigned short Bs[128 * 64];
  const int b = blockIdx.x;
  if (b < 64) {  // pass0: out += C0@Ws1, split-K4
    const int z = b >> 4, bm = (b >> 1) & 7, bn = b & 1;
    gemm_core<1, 64>(C0 + z * 256, 1024, WT1s + z * 256, 1024, 256,
                     (long)bm * 128, (long)bn * 128, 0, nullptr, nullptr, out, 256, As, Bs);
  } else {  // pass1: A staged from P with inline mean25 (col0 = z*256)
    const int u = b - 64;
    const int z = u >> 4, bm = (u >> 1) & 7, bn = u & 1;
    gemm_core<2, 64>(nullptr, 0, WT1n + z * 256, 1024, 256,
                     (long)bm * 128, (long)bn * 128, z * 256, nullptr, P, out, 256, As, Bs);
  }
}

extern "C" void kernel_launch(void* const* d_in, const int* in_sizes, int n_in,
                              void* d_out, int out_size, void* d_ws, size_t ws_size,
                              hipStream_t stream) {
  const float* x      = (const float*)d_in[0];   // [200000, 512]
  const int*   nodes  = (const int*)d_in[1];     // [1024]
  const int*   neigh1 = (const int*)d_in[2];     // [25600]
  const int*   neigh2 = (const int*)d_in[3];     // [256000]
  const float* Ws0    = (const float*)d_in[4];   // [512, 512]
  const float* Wn0    = (const float*)d_in[5];   // [512, 512]
  const float* Ws1    = (const float*)d_in[6];   // [1024, 256]
  const float* Wn1    = (const float*)d_in[7];   // [1024, 256]
  float* out = (float*)d_out;                    // [1024, 256]

  char* p = (char*)d_ws;
  unsigned short* WT0s  = (unsigned short*)p; p += (size_t)512 * 512 * 2;
  unsigned short* WT0n  = (unsigned short*)p; p += (size_t)512 * 512 * 2;
  unsigned short* WT1s  = (unsigned short*)p; p += (size_t)256 * 1024 * 2;
  unsigned short* WT1n  = (unsigned short*)p; p += (size_t)256 * 1024 * 2;
  unsigned short* Hall  = (unsigned short*)p; p += (size_t)26624 * 512 * 2;
  unsigned short* Hmall = (unsigned short*)p; p += (size_t)26624 * 512 * 2;
  unsigned short* C0    = (unsigned short*)p; p += (size_t)1024 * 1024 * 2;
  float*          P     = (float*)p;          p += (size_t)400 * 4 * 1024 * 4;

  hipLaunchKernelGGL(phase0_kernel, dim3(17664), dim3(256), 0, stream,
                     x, neigh1, nodes, Ws0, Wn0, Ws1, Wn1,
                     Hall, WT0s, WT0n, WT1s, WT1n, out);
  hipLaunchKernelGGL(phase1_kernel, dim3(14144), dim3(256), 0, stream,
                     x, neigh2, Hall, WT0s, Hmall, C0, P);
  hipLaunchKernelGGL(phase2_kernel, dim3(832), dim3(256), 0, stream,
                     Hmall, WT0n, C0, P);
  hipLaunchKernelGGL(phaseD_kernel, dim3(128), dim3(256), 0, stream,
                     C0, WT1s, WT1n, P, out);
}

// Round 17
// 170.102 us; speedup vs baseline: 15.2169x; 1.0199x over previous
//
#include <hip/hip_runtime.h>
#include <hip/hip_bf16.h>

// GraphSAGE inference, MI355X. R17 = R14 (best measured: 170.2 us), restored.
//  P0: gather_self(Hall) | weights cast | zero(out)
//  P1: gemm0-SELF (XCD-clustered; rows<25600 -> P partials, rows>=25600 -> C0)
//      || gather_mean10 || mean25(Hall)->H0m
//  P2: gemm0-NEIGHBOR (same epilogue, cols 512+)
//  PD: reduce P -> M1 (bf16, /25) | gemm1-pass0 (C0@Ws1, split-K4, atomics)
//  PE: gemm1-pass1 (M1@Wn1, split-K4, atomics)
// P layout: P[wh][slot][1024] f32, wh = 64-row half-tile (0..399), slot = local
// group (0..3). Each slot written exactly once (no atomics).

#define DEVINL __device__ __forceinline__

typedef __bf16 bf16x8 __attribute__((ext_vector_type(8)));
typedef float f32x4 __attribute__((ext_vector_type(4)));

DEVINL unsigned short f2bf(float f) {
  union { float f; unsigned u; } v; v.f = f;
  unsigned r = v.u + 0x7FFFu + ((v.u >> 16) & 1u);  // RNE
  return (unsigned short)(r >> 16);
}
DEVINL float bf2f(unsigned short h) {
  union { unsigned u; float f; } v; v.u = ((unsigned)h) << 16;
  return v.f;
}

DEVINL void gload_lds16(const void* g, void* l) {
  __builtin_amdgcn_global_load_lds(
      (const __attribute__((address_space(1))) void*)g,
      (__attribute__((address_space(3))) void*)l, 16, 0, 0);
}

// ---- NT GEMM core: 128x128 tile, BK in {32,64}, 4 waves 2x2, 16x16x32 bf16 MFMA.
// EPI 0 (layer0): rows<25600 -> static-reg group-sum -> P[wh][slot][col] (relu'd);
//                 rows>=25600 -> bf16 store to C0[row-25600][col0+...].
// EPI 1 (layer1): f32 atomicAdd into out (split-K).
template <int EPI, int BK>
DEVINL void gemm_core(const unsigned short* __restrict__ A, int lda,
                      const unsigned short* __restrict__ Bt, int ldb,
                      int Kc, long tm, long tn, int col0,
                      unsigned short* __restrict__ C0, float* __restrict__ P,
                      float* __restrict__ out, int ldc,
                      unsigned short* As, unsigned short* Bs) {
  const int t = threadIdx.x;
  const int w = t >> 6;
  const int l = t & 63;
  const int wm = w >> 1, wn = w & 1;
  f32x4 acc[4][4] = {};
  constexpr int LPR = BK / 8;            // lanes per row (16B chunks)
  constexpr int RPW = 64 / LPR;          // rows per wave-gload
  constexpr int ROUNDS = 128 / (4 * RPW);
  constexpr int NS = BK / 32;            // k-slices per iter
  const int s_r = l / LPR;
  const int s_kc = (l % LPR) * 8;

  for (int kt = 0; kt < Kc; kt += BK) {
    __syncthreads();  // LDS free
    #pragma unroll
    for (int r = 0; r < ROUNDS; ++r) {
      const int chunk = r * (4 * RPW) + w * RPW;
      gload_lds16(A + (size_t)(tm + chunk + s_r) * lda + kt + s_kc, As + chunk * BK);
      gload_lds16(Bt + (size_t)(tn + chunk + s_r) * ldb + kt + s_kc, Bs + chunk * BK);
    }
    __syncthreads();  // staged (barrier drains vmcnt)

    bf16x8 af[4][NS], bfr[4][NS];
    const unsigned short* Ab = As + ((size_t)(wm * 64 + (l & 15)) * BK + (l >> 4) * 8);
    const unsigned short* Bb = Bs + ((size_t)(wn * 64 + (l & 15)) * BK + (l >> 4) * 8);
    #pragma unroll
    for (int f = 0; f < 4; ++f)
      #pragma unroll
      for (int s = 0; s < NS; ++s) {
        af[f][s] = *reinterpret_cast<const bf16x8*>(Ab + f * 16 * BK + s * 32);
        bfr[f][s] = *reinterpret_cast<const bf16x8*>(Bb + f * 16 * BK + s * 32);
      }
    #pragma unroll
    for (int s = 0; s < NS; ++s)   // K ascending (matches prior rounds' numerics)
      #pragma unroll
      for (int i = 0; i < 4; ++i)
        #pragma unroll
        for (int j = 0; j < 4; ++j)
          acc[i][j] = __builtin_amdgcn_mfma_f32_16x16x32_bf16(af[i][s], bfr[j][s], acc[i][j], 0, 0, 0);
  }

  // epilogue: C/D layout col = l&15, row = (l>>4)*4 + r  [m89/m91 verified]
  const int q = l >> 4, cl = l & 15;
  if (EPI == 0) {
    if (tm < 25600) {
      // register group-sum, ALL indices compile-time (rule #20: no scratch).
      const int wmBase = (int)tm + wm * 64;
      const int g0w = wmBase / 25;
      float gacc[4][4] = {};  // [j][slot], statically indexed only
      #pragma unroll
      for (int i = 0; i < 4; ++i)
        #pragma unroll
        for (int r = 0; r < 4; ++r) {
          const int gl = (wmBase + i * 16 + q * 4 + r) / 25 - g0w;  // runtime 0..3
          #pragma unroll
          for (int j = 0; j < 4; ++j) {
            const float v = fmaxf(acc[i][j][r], 0.f);
            #pragma unroll
            for (int slot = 0; slot < 4; ++slot)
              gacc[j][slot] += (gl == slot) ? v : 0.f;   // cndmask+add
          }
        }
      // reduce across the 4 q-lanes (l bits 4..5)
      #pragma unroll
      for (int j = 0; j < 4; ++j)
        #pragma unroll
        for (int slot = 0; slot < 4; ++slot) {
          float v = gacc[j][slot];
          v += __shfl_xor(v, 16);
          v += __shfl_xor(v, 32);
          gacc[j][slot] = v;
        }
      if (q == 0) {  // 16 lanes x 4 j x 4 slots
        const int wh = wmBase >> 6;
        #pragma unroll
        for (int slot = 0; slot < 4; ++slot)
          #pragma unroll
          for (int j = 0; j < 4; ++j)
            P[((size_t)wh * 4 + slot) * 1024 + col0 + tn + wn * 64 + j * 16 + cl] = gacc[j][slot];
      }
    } else {
      #pragma unroll
      for (int i = 0; i < 4; ++i)
        #pragma unroll
        for (int j = 0; j < 4; ++j)
          #pragma unroll
          for (int r = 0; r < 4; ++r) {
            const long row = tm - 25600 + wm * 64 + i * 16 + q * 4 + r;
            const long col = col0 + tn + wn * 64 + j * 16 + cl;
            C0[row * 1024 + col] = f2bf(fmaxf(acc[i][j][r], 0.f));
          }
    }
  } else {
    #pragma unroll
    for (int i = 0; i < 4; ++i)
      #pragma unroll
      for (int j = 0; j < 4; ++j)
        #pragma unroll
        for (int r = 0; r < 4; ++r) {
          const long row = tm + wm * 64 + i * 16 + q * 4 + r;
          const long col = tn + wn * 64 + j * 16 + cl;
          atomicAdd(out + row * ldc + col, acc[i][j][r]);
        }
  }
}

// XCD-clustered tile map for 832 = 208 rowblocks x 4 colblocks (R11, kept).
DEVINL void xcd_tile_map(int b, long& tm, long& tn) {
  const int xcd = b & 7, idx = b >> 3;
  tm = (long)(xcd + 8 * (idx >> 2)) * 128;
  tn = (long)(idx & 3) * 128;
}

// ---- mean10 of x rows -> bf16 Hmall row (2 rows/block, 256 thr)
DEVINL void mean10_row(const float* __restrict__ x, const int* __restrict__ neigh2,
                       unsigned short* __restrict__ Hmall, int row, int tid) {
  int c4 = (tid & 127) << 2;
  float4 acc = {0.f, 0.f, 0.f, 0.f};
  const int* ip = neigh2 + (size_t)row * 10;
  #pragma unroll
  for (int j = 0; j < 10; ++j) {
    const float4 v = *reinterpret_cast<const float4*>(x + (size_t)ip[j] * 512 + c4);
    acc.x += v.x; acc.y += v.y; acc.z += v.z; acc.w += v.w;
  }
  const float s = 0.1f;
  ushort4 o; o.x = f2bf(acc.x * s); o.y = f2bf(acc.y * s);
  o.z = f2bf(acc.z * s); o.w = f2bf(acc.w * s);
  *reinterpret_cast<ushort4*>(Hmall + (size_t)row * 512 + c4) = o;
}

// ---- P0: gather_self (13312) | weights cast (4096) | zero out (256)
__global__ __launch_bounds__(256) void phase0_kernel(
    const float* __restrict__ x, const int* __restrict__ neigh1, const int* __restrict__ nodes,
    const float* __restrict__ Ws0, const float* __restrict__ Wn0,
    const float* __restrict__ Ws1, const float* __restrict__ Wn1,
    unsigned short* __restrict__ Hall,
    unsigned short* __restrict__ WT0s, unsigned short* __restrict__ WT0n,
    unsigned short* __restrict__ WT1s, unsigned short* __restrict__ WT1n,
    float* __restrict__ out) {
  const int b = blockIdx.x;
  const int tid = threadIdx.x;
  if (b < 13312) {  // gather_self: 2 rows/block
    int row = b * 2 + (tid >> 7);
    int src = row < 25600 ? neigh1[row] : nodes[row - 25600];
    int c4 = (tid & 127) << 2;
    const float4 v = *reinterpret_cast<const float4*>(x + (size_t)src * 512 + c4);
    ushort4 o; o.x = f2bf(v.x); o.y = f2bf(v.y); o.z = f2bf(v.z); o.w = f2bf(v.w);
    *reinterpret_cast<ushort4*>(Hall + (size_t)row * 512 + c4) = o;
  } else if (b < 13312 + 4096) {  // weights -> bf16 [N][K]
    int t = (b - 13312) * 256 + tid;
    int region = t >> 18, local = t & 262143;
    const float* W; unsigned short* WT;
    if (region == 0)      { W = Ws0; WT = WT0s; }
    else if (region == 1) { W = Wn0; WT = WT0n; }
    else if (region == 2) { W = Ws1; WT = WT1s; }
    else                  { W = Wn1; WT = WT1n; }
    int k, n, N;
    if (region < 2) { k = local & 511;  n = local >> 9;  N = 512; }
    else            { k = local & 1023; n = local >> 10; N = 256; }
    WT[local] = f2bf(W[(size_t)k * N + n]);
  } else {  // zero out (1 MB)
    int t = (b - 17408) * 256 + tid;
    reinterpret_cast<float4*>(out)[t] = float4{0.f, 0.f, 0.f, 0.f};
  }
}

// ---- P1: gemm0-self (832, XCD-clustered) | gather_mean10 (12800) | mean25(Hall)->H0m (512)
__global__ __launch_bounds__(256) void phase1_kernel(
    const float* __restrict__ x, const int* __restrict__ neigh2,
    const unsigned short* __restrict__ Hall, const unsigned short* __restrict__ WT0s,
    unsigned short* __restrict__ Hmall,
    unsigned short* __restrict__ C0, float* __restrict__ P) {
  __shared__ __align__(16) unsigned short As[128 * 32];
  __shared__ __align__(16) unsigned short Bs[128 * 32];
  const int b = blockIdx.x;
  const int tid = threadIdx.x;
  if (b < 832) {  // self half: cols 0-511, all 26624 rows
    long tm, tn;
    xcd_tile_map(b, tm, tn);
    gemm_core<0, 32>(Hall, 512, WT0s, 512, 512, tm, tn, 0, C0, P, nullptr, 0, As, Bs);
  } else if (b < 832 + 12800) {  // mean10 rows 0-25599
    mean10_row(x, neigh2, Hmall, (b - 832) * 2 + (tid >> 7), tid);
  } else {  // H0m = mean25 of Hall bf16 rows -> Hmall rows 25600+
    int g = (b - 13632) * 2 + (tid >> 7);
    int c4 = (tid & 127) << 2;
    float a0 = 0, a1 = 0, a2 = 0, a3 = 0;
    for (int j = 0; j < 25; ++j) {
      ushort4 v = *reinterpret_cast<const ushort4*>(Hall + ((size_t)g * 25 + j) * 512 + c4);
      a0 += bf2f(v.x); a1 += bf2f(v.y); a2 += bf2f(v.z); a3 += bf2f(v.w);
    }
    const float s = 1.0f / 25.0f;
    ushort4 o; o.x = f2bf(a0 * s); o.y = f2bf(a1 * s); o.z = f2bf(a2 * s); o.w = f2bf(a3 * s);
    *reinterpret_cast<ushort4*>(Hmall + ((size_t)25600 + g) * 512 + c4) = o;
  }
}

// ---- P2: gemm0 neighbor half (832, XCD-clustered): cols 512-1023
__global__ __launch_bounds__(256) void phase2_kernel(
    const unsigned short* __restrict__ Hmall, const unsigned short* __restrict__ WT0n,
    unsigned short* __restrict__ C0, float* __restrict__ P) {
  __shared__ __align__(16) unsigned short As[128 * 32];
  __shared__ __align__(16) unsigned short Bs[128 * 32];
  long tm, tn;
  xcd_tile_map(blockIdx.x, tm, tn);
  gemm_core<0, 32>(Hmall, 512, WT0n, 512, 512, tm, tn, 512, C0, P, nullptr, 0, As, Bs);
}

// ---- PD: reduce P -> M1 (1024 blocks) | gemm1-pass0 (64 blocks)
__global__ __launch_bounds__(256) void phaseD_kernel(
    const float* __restrict__ P, unsigned short* __restrict__ M1,
    const unsigned short* __restrict__ C0, const unsigned short* __restrict__ WT1s,
    float* __restrict__ out) {
  __shared__ __align__(16) unsigned short As[128 * 64];
  __shared__ __align__(16) unsigned short Bs[128 * 64];
  const int b = blockIdx.x;
  if (b < 1024) {  // M1[g][:] = bf16( (sum of <=2 partials) / 25 )
    const int g = b;
    const int c = threadIdx.x << 2;
    const int r0 = g * 25, r1 = g * 25 + 24;
    const int wh0 = r0 >> 6, wh1 = r1 >> 6;
    f32x4 s = {0.f, 0.f, 0.f, 0.f};
    for (int wh = wh0; wh <= wh1; ++wh) {
      const int slot = g - (wh * 64) / 25;   // 0..3 by construction
      const f32x4 v = *reinterpret_cast<const f32x4*>(P + ((size_t)wh * 4 + slot) * 1024 + c);
      s[0] += v[0]; s[1] += v[1]; s[2] += v[2]; s[3] += v[3];
    }
    const float sc = 1.0f / 25.0f;
    ushort4 o; o.x = f2bf(s[0] * sc); o.y = f2bf(s[1] * sc);
    o.z = f2bf(s[2] * sc); o.w = f2bf(s[3] * sc);
    *reinterpret_cast<ushort4*>(M1 + (size_t)g * 1024 + c) = o;
  } else {  // out += C0@Ws1, split-K4
    const int u = b - 1024;
    const int z = u >> 4, bm = (u >> 1) & 7, bn = u & 1;
    gemm_core<1, 64>(C0 + z * 256, 1024, WT1s + z * 256, 1024, 256,
                     (long)bm * 128, (long)bn * 128, 0, nullptr, nullptr, out, 256, As, Bs);
  }
}

// ---- PE: gemm1-pass1 (64): out += M1@Wn1, split-K4
__global__ __launch_bounds__(256) void phaseE_kernel(
    const unsigned short* __restrict__ M1, const unsigned short* __restrict__ WT1n,
    float* __restrict__ out) {
  __shared__ __align__(16) unsigned short As[128 * 64];
  __shared__ __align__(16) unsigned short Bs[128 * 64];
  const int b = blockIdx.x;
  const int z = b >> 4, bm = (b >> 1) & 7, bn = b & 1;
  gemm_core<1, 64>(M1 + z * 256, 1024, WT1n + z * 256, 1024, 256,
                   (long)bm * 128, (long)bn * 128, 0, nullptr, nullptr, out, 256, As, Bs);
}

extern "C" void kernel_launch(void* const* d_in, const int* in_sizes, int n_in,
                              void* d_out, int out_size, void* d_ws, size_t ws_size,
                              hipStream_t stream) {
  const float* x      = (const float*)d_in[0];   // [200000, 512]
  const int*   nodes  = (const int*)d_in[1];     // [1024]
  const int*   neigh1 = (const int*)d_in[2];     // [25600]
  const int*   neigh2 = (const int*)d_in[3];     // [256000]
  const float* Ws0    = (const float*)d_in[4];   // [512, 512]
  const float* Wn0    = (const float*)d_in[5];   // [512, 512]
  const float* Ws1    = (const float*)d_in[6];   // [1024, 256]
  const float* Wn1    = (const float*)d_in[7];   // [1024, 256]
  float* out = (float*)d_out;                    // [1024, 256]

  char* p = (char*)d_ws;
  unsigned short* WT0s  = (unsigned short*)p; p += (size_t)512 * 512 * 2;
  unsigned short* WT0n  = (unsigned short*)p; p += (size_t)512 * 512 * 2;
  unsigned short* WT1s  = (unsigned short*)p; p += (size_t)256 * 1024 * 2;
  unsigned short* WT1n  = (unsigned short*)p; p += (size_t)256 * 1024 * 2;
  unsigned short* Hall  = (unsigned short*)p; p += (size_t)26624 * 512 * 2;
  unsigned short* Hmall = (unsigned short*)p; p += (size_t)26624 * 512 * 2;
  unsigned short* C0    = (unsigned short*)p; p += (size_t)1024 * 1024 * 2;
  unsigned short* M1    = (unsigned short*)p; p += (size_t)1024 * 1024 * 2;
  float*          P     = (float*)p;          p += (size_t)400 * 4 * 1024 * 4;

  hipLaunchKernelGGL(phase0_kernel, dim3(17664), dim3(256), 0, stream,
                     x, neigh1, nodes, Ws0, Wn0, Ws1, Wn1,
                     Hall, WT0s, WT0n, WT1s, WT1n, out);
  hipLaunchKernelGGL(phase1_kernel, dim3(14144), dim3(256), 0, stream,
                     x, neigh2, Hall, WT0s, Hmall, C0, P);
  hipLaunchKernelGGL(phase2_kernel, dim3(832), dim3(256), 0, stream,
                     Hmall, WT0n, C0, P);
  hipLaunchKernelGGL(phaseD_kernel, dim3(1088), dim3(256), 0, stream,
                     P, M1, C0, WT1s, out);
  hipLaunchKernelGGL(phaseE_kernel, dim3(64), dim3(256), 0, stream,
                     M1, WT1n, out);
}